// Round 2
// baseline (1032.711 us; speedup 1.0000x reference)
//
#include <hip/hip_runtime.h>

typedef float v2 __attribute__((ext_vector_type(2)));

#define BLK 256

static __device__ __forceinline__ v2 mkv2(float a, float b){ v2 r; r.x = a; r.y = b; return r; }

template<int N>
static __device__ __forceinline__ float dotN(const v2* __restrict__ w, const v2* in){
    v2 a = {0.f, 0.f};
    #pragma unroll
    for (int k = 0; k < N; ++k) a += in[k] * w[k];
    return a.x + a.y;
}

// Pad sW1 (41x41), sW2 (41x41), sW3 (22x41) to row-stride 42 with zero in col 41,
// so packed (v2) weight loads are 8B-aligned and the pair count is uniform (21).
__global__ void prep_pad(const float* __restrict__ sW1,
                         const float* __restrict__ sW2,
                         const float* __restrict__ sW3,
                         float* __restrict__ wp)
{
    int i = blockIdx.x * 256 + threadIdx.x;
    if (i >= 4368) return;
    float v;
    if (i < 1722) {
        int o = i / 42, j = i - o * 42;
        v = (j < 41) ? sW1[o * 41 + j] : 0.f;
    } else if (i < 3444) {
        int k = i - 1722; int o = k / 42, j = k - o * 42;
        v = (j < 41) ? sW2[o * 41 + j] : 0.f;
    } else {
        int k = i - 3444; int o = k / 42, j = k - o * 42;
        v = (j < 41) ? sW3[o * 41 + j] : 0.f;
    }
    wp[i] = v;
}

__global__ __launch_bounds__(BLK, 3) void ran_fused(
    const float* __restrict__ x,
    const float* __restrict__ bW1, const float* __restrict__ bb1,
    const float* __restrict__ bW2, const float* __restrict__ bb2,
    const float* __restrict__ bW3, const float* __restrict__ bb3,
    const float* __restrict__ sWp,   // padded: sW1p@0, sW2p@1722, sW3p@3444, row stride 42
    const float* __restrict__ sb1, const float* __restrict__ sb2,
    const float* __restrict__ sb3,
    float* __restrict__ out)
{
    __shared__ v2    xt[BLK * 21];   // 256 rows x 42 floats (40 data + 2 pad), 8B units
    __shared__ float ia[10 * BLK];   // iab via LDS: allows runtime slot index
    const int t    = threadIdx.x;
    const int row0 = blockIdx.x * BLK;
    const float4* __restrict__ xg = (const float4*)x;

    // ---- chunk 0: x_iabs = x[:, 0:40] (coalesced float4 -> LDS) ----
    #pragma unroll
    for (int i = 0; i < 10; ++i) {
        int f = t + BLK * i;              // 0..2559 over the 256x10 float4 tile
        int r = f / 10, c = f - r * 10;
        float4 v = xg[(row0 + r) * 110 + c];
        xt[r * 21 + 2 * c]     = mkv2(v.x, v.y);
        xt[r * 21 + 2 * c + 1] = mkv2(v.z, v.w);
    }
    __syncthreads();

    v2 xr[20];
    #pragma unroll
    for (int k = 0; k < 20; ++k) xr[k] = xt[t * 21 + k];

    // ---- big MLP: 40 -> 40 -> 40 -> 10, softmax ----
    v2 h1[20];
    #pragma unroll
    for (int o = 0; o < 20; ++o) {
        float r0 = fmaxf(bb1[2*o]   + dotN<20>((const v2*)(bW1 + (2*o)*40),   xr), 0.f);
        float r1 = fmaxf(bb1[2*o+1] + dotN<20>((const v2*)(bW1 + (2*o+1)*40), xr), 0.f);
        h1[o] = mkv2(r0, r1);
    }
    v2 h2[20];
    #pragma unroll
    for (int o = 0; o < 20; ++o) {
        float r0 = fmaxf(bb2[2*o]   + dotN<20>((const v2*)(bW2 + (2*o)*40),   h1), 0.f);
        float r1 = fmaxf(bb2[2*o+1] + dotN<20>((const v2*)(bW2 + (2*o+1)*40), h1), 0.f);
        h2[o] = mkv2(r0, r1);
    }
    float lg[10];
    #pragma unroll
    for (int o = 0; o < 10; ++o)
        lg[o] = bb3[o] + dotN<20>((const v2*)(bW3 + o * 40), h2);

    float mx = lg[0];
    #pragma unroll
    for (int o = 1; o < 10; ++o) mx = fmaxf(mx, lg[o]);
    float ssum = 0.f;
    float ev[10];
    #pragma unroll
    for (int o = 0; o < 10; ++o) { ev[o] = __expf(lg[o] - mx); ssum += ev[o]; }
    float rs = __fdividef(1.f, ssum);
    #pragma unroll
    for (int o = 0; o < 10; ++o) ia[o * BLK + t] = ev[o] * rs;  // own-thread slot, no barrier needed

    // ---- small MLP per slot: [x_ues_s(40), iab_s] -> 41 -> 41 -> 22 softmax * iab_s ----
    for (int s = 0; s < 10; ++s) {
        __syncthreads();                 // xt free (previous readers done)
        #pragma unroll
        for (int i = 0; i < 10; ++i) {
            int f = t + BLK * i;
            int r = f / 10, c = f - r * 10;
            float4 v = xg[(row0 + r) * 110 + 10 + s * 10 + c];
            xt[r * 21 + 2 * c]     = mkv2(v.x, v.y);
            xt[r * 21 + 2 * c + 1] = mkv2(v.z, v.w);
        }
        __syncthreads();

        float iv = ia[s * BLK + t];
        v2 xs[21];
        #pragma unroll
        for (int k = 0; k < 20; ++k) xs[k] = xt[t * 21 + k];
        xs[20] = mkv2(iv, 0.f);
        __syncthreads();                 // xs reads done; xt reusable as out tile

        v2 g1[21];
        #pragma unroll
        for (int o = 0; o < 20; ++o) {
            float r0 = fmaxf(sb1[2*o]   + dotN<21>((const v2*)(sWp + (2*o)*42),   xs), 0.f);
            float r1 = fmaxf(sb1[2*o+1] + dotN<21>((const v2*)(sWp + (2*o+1)*42), xs), 0.f);
            g1[o] = mkv2(r0, r1);
        }
        g1[20] = mkv2(fmaxf(sb1[40] + dotN<21>((const v2*)(sWp + 40*42), xs), 0.f), 0.f);

        v2 g2[21];
        #pragma unroll
        for (int o = 0; o < 20; ++o) {
            float r0 = fmaxf(sb2[2*o]   + dotN<21>((const v2*)(sWp + 1722 + (2*o)*42),   g1), 0.f);
            float r1 = fmaxf(sb2[2*o+1] + dotN<21>((const v2*)(sWp + 1722 + (2*o+1)*42), g1), 0.f);
            g2[o] = mkv2(r0, r1);
        }
        g2[20] = mkv2(fmaxf(sb2[40] + dotN<21>((const v2*)(sWp + 1722 + 40*42), g1), 0.f), 0.f);

        float l3[22];
        #pragma unroll
        for (int o = 0; o < 22; ++o)
            l3[o] = sb3[o] + dotN<21>((const v2*)(sWp + 3444 + o * 42), g2);

        float m2 = l3[0];
        #pragma unroll
        for (int o = 1; o < 22; ++o) m2 = fmaxf(m2, l3[o]);
        float s2 = 0.f;
        float e2[22];
        #pragma unroll
        for (int o = 0; o < 22; ++o) { e2[o] = __expf(l3[o] - m2); s2 += e2[o]; }
        float sc = __fdividef(iv, s2);   // iab_s / sum

        // stage 22 outputs in xt (cols 0..10 as v2), then coalesced store
        #pragma unroll
        for (int c = 0; c < 11; ++c) xt[t * 21 + c] = mkv2(e2[2*c] * sc, e2[2*c+1] * sc);
        __syncthreads();

        float2* __restrict__ og = (float2*)out;
        #pragma unroll
        for (int i = 0; i < 11; ++i) {
            int f = t + BLK * i;          // 0..2815 over the 256x11 float2 tile
            int r = f / 11, c = f - r * 11;
            v2 v = xt[r * 21 + c];
            og[(row0 + r) * 110 + s * 11 + c] = make_float2(v.x, v.y);
        }
    }
}

extern "C" void kernel_launch(void* const* d_in, const int* in_sizes, int n_in,
                              void* d_out, int out_size, void* d_ws, size_t ws_size,
                              hipStream_t stream)
{
    (void)n_in; (void)out_size; (void)ws_size;
    const float* x   = (const float*)d_in[0];
    const float* bW1 = (const float*)d_in[1];
    const float* bb1 = (const float*)d_in[2];
    const float* bW2 = (const float*)d_in[3];
    const float* bb2 = (const float*)d_in[4];
    const float* bW3 = (const float*)d_in[5];
    const float* bb3 = (const float*)d_in[6];
    const float* sW1 = (const float*)d_in[7];
    const float* sb1 = (const float*)d_in[8];
    const float* sW2 = (const float*)d_in[9];
    const float* sb2 = (const float*)d_in[10];
    const float* sW3 = (const float*)d_in[11];
    const float* sb3 = (const float*)d_in[12];
    float* out = (float*)d_out;
    float* wp  = (float*)d_ws;

    prep_pad<<<18, 256, 0, stream>>>(sW1, sW2, sW3, wp);

    const int rows = in_sizes[0] / 440;           // 262144
    ran_fused<<<rows / BLK, BLK, 0, stream>>>(x, bW1, bb1, bW2, bb2, bW3, bb3,
                                              wp, sb1, sb2, sb3, out);
}